// Round 11
// baseline (179.431 us; speedup 1.0000x reference)
//
#include <hip/hip_runtime.h>
#include <math.h>

#define BB 8
#define NN 1024
#define DD 64
#define EPSF 0.05f
#define MAX_ITER 100
// threshold on SUM of |du| over B*N (reference: mean < 1e-6)
// fixed-point: units of 2^-20; 8.192e-3 * 2^20 = 8589.9 -> 8590
#define ERR_FX_THRESH 8590u
// 1/(eps*ln2) and eps*ln2
#define SCALE_ 28.853900817779268f
#define EPSLN2_ 0.034657359027997264f
#define NBLK 256
#define NPER 32    // blocks per batch barrier
#define MPITCH 1032 // Mslab pitch in shorts: 2064B rows == 4 banks/row (proven geometry)

typedef __attribute__((ext_vector_type(8))) short short8;
typedef __attribute__((ext_vector_type(4))) float f32x4;

static __device__ __forceinline__ float fexp2(float x) { return __builtin_amdgcn_exp2f(x); }
static __device__ __forceinline__ float flog2(float x) { return __builtin_amdgcn_logf(x); }
static __device__ __forceinline__ float bflo(unsigned u) { return __uint_as_float(u << 16); }
static __device__ __forceinline__ unsigned short bf16rne(float x) {
    unsigned u = __float_as_uint(x);
    u += 0x7fffu + ((u >> 16) & 1u);
    return (unsigned short)(u >> 16);
}
__device__ __forceinline__ float wave_sum64(float x) {
#pragma unroll
    for (int off = 1; off < 64; off <<= 1) x += __shfl_xor(x, off);
    return x;
}

// ---- metadata: u/v floats (64KB) + cnt64 (12.8KB) = 78,336B past the two 16MB
//      matrices (proven bound). PER-BATCH counter stripes (1600B apart -> distinct
//      XCD-local lines). Protocol law (R2/R3/R6): 32 writers + 32 pollers on ONE
//      line per phase is optimal; every deviation tested lost 1.6-4x. ----
// cnt64[b*200+p]: high32 = block-arrival count for phase p of batch b,
//                 low32  = fixed-point err sum (u-phases, 2^-20 units, per-block ceil)
#define CNT64IDX(p, b) ((b) * 200 + (p))

// ---------------- pre-normalize: Qn/Kn = bf16(l2norm(q/k)), ONCE per row (R10-proven) ----------------
__global__ __launch_bounds__(256) void norm_kernel(const float* __restrict__ q,
                                                   const float* __restrict__ k,
                                                   unsigned short* __restrict__ Qn,
                                                   unsigned short* __restrict__ Kn) {
    int tid = threadIdx.x;
    int bi = blockIdx.x;                 // 0..127 -> q rows, 128..255 -> k rows
    const float* src = (bi < 128) ? q : k;
    unsigned short* dst = (bi < 128) ? Qn : Kn;
    int row = (bi & 127) * 64 + (tid >> 2);   // 64 rows per block, 4 threads/row
    int c = tid & 3;                          // 16-float chunk within row
    const float* rp = src + ((size_t)row << 6) + c * 16;
    float4 x0 = ((const float4*)rp)[0];
    float4 x1 = ((const float4*)rp)[1];
    float4 x2 = ((const float4*)rp)[2];
    float4 x3 = ((const float4*)rp)[3];
    float ss = x0.x * x0.x + x0.y * x0.y + x0.z * x0.z + x0.w * x0.w
             + x1.x * x1.x + x1.y * x1.y + x1.z * x1.z + x1.w * x1.w
             + x2.x * x2.x + x2.y * x2.y + x2.z * x2.z + x2.w * x2.w
             + x3.x * x3.x + x3.y * x3.y + x3.z * x3.z + x3.w * x3.w;
    ss += __shfl_xor(ss, 1);
    ss += __shfl_xor(ss, 2);             // 4-lane groups are xor-closed
    float sc = 1.0f / fmaxf(sqrtf(ss), 1e-12f);
    unsigned pk[8];
    pk[0] = (unsigned)bf16rne(x0.x * sc) | ((unsigned)bf16rne(x0.y * sc) << 16);
    pk[1] = (unsigned)bf16rne(x0.z * sc) | ((unsigned)bf16rne(x0.w * sc) << 16);
    pk[2] = (unsigned)bf16rne(x1.x * sc) | ((unsigned)bf16rne(x1.y * sc) << 16);
    pk[3] = (unsigned)bf16rne(x1.z * sc) | ((unsigned)bf16rne(x1.w * sc) << 16);
    pk[4] = (unsigned)bf16rne(x2.x * sc) | ((unsigned)bf16rne(x2.y * sc) << 16);
    pk[5] = (unsigned)bf16rne(x2.z * sc) | ((unsigned)bf16rne(x2.w * sc) << 16);
    pk[6] = (unsigned)bf16rne(x3.x * sc) | ((unsigned)bf16rne(x3.y * sc) << 16);
    pk[7] = (unsigned)bf16rne(x3.z * sc) | ((unsigned)bf16rne(x3.w * sc) << 16);
    unsigned short* op = dst + ((size_t)row << 6) + c * 16;
    ((uint4*)op)[0] = make_uint4(pk[0], pk[1], pk[2], pk[3]);
    ((uint4*)op)[1] = make_uint4(pk[4], pk[5], pk[6], pk[7]);
}

// ---------------- cost + exp via MFMA (R10-proven, verbatim) ----------------
__global__ __launch_bounds__(256) void cost_kernel(const unsigned short* __restrict__ Qn,
                                                   const unsigned short* __restrict__ Kn,
                                                   unsigned short* __restrict__ M,
                                                   unsigned short* __restrict__ MT,
                                                   float* __restrict__ vz) {
    __shared__ __align__(16) unsigned short Qb[64][72];   // pitch 72: 2-way conflict = free
    __shared__ __align__(16) unsigned short Kb[64][72];
    __shared__ __align__(16) unsigned short Ms[64][72];   // M tile staging
    __shared__ __align__(16) unsigned short MsT[64][72];  // MT tile staging
    int b = blockIdx.z;
    int i0 = blockIdx.y * 64, j0 = blockIdx.x * 64;
    int tid = threadIdx.x;
    if (blockIdx.x == 0 && blockIdx.y == 0 && blockIdx.z == 0) {
        // zero v (8192 f) + cnt64 (3200 words) = 11392 words = 2848 float4
        float4 z4 = {0.f, 0.f, 0.f, 0.f};
        for (int i = tid; i < 2848; i += 256) ((float4*)vz)[i] = z4;
    }
    // load 64x64 bf16 tiles of Qn and Kn (8KB each), coalesced uint4
#pragma unroll
    for (int s = 0; s < 2; ++s) {
        int idx = tid + 256 * s;
        int row = idx >> 3, seg = idx & 7;
        *(uint4*)&Qb[row][seg * 8] =
            *(const uint4*)(Qn + (((size_t)b * NN + i0 + row) << 6) + seg * 8);
        *(uint4*)&Kb[row][seg * 8] =
            *(const uint4*)(Kn + (((size_t)b * NN + j0 + row) << 6) + seg * 8);
    }
    __syncthreads();
    int w = tid >> 6, lane = tid & 63;
    int m = lane & 15, qq = lane >> 4;
    int rloc = w * 16;
    short8 a0 = *(const short8*)&Qb[rloc + m][qq * 8];
    short8 a1 = *(const short8*)&Qb[rloc + m][qq * 8 + 32];
    f32x4 acc[4];
#pragma unroll
    for (int nt = 0; nt < 4; ++nt) {
        short8 b0 = *(const short8*)&Kb[nt * 16 + m][qq * 8];
        short8 b1 = *(const short8*)&Kb[nt * 16 + m][qq * 8 + 32];
        f32x4 z = {0.f, 0.f, 0.f, 0.f};
        z = __builtin_amdgcn_mfma_f32_16x16x32_bf16(a0, b0, z, 0, 0, 0);
        acc[nt] = __builtin_amdgcn_mfma_f32_16x16x32_bf16(a1, b1, z, 0, 0, 0);
    }
#pragma unroll
    for (int nt = 0; nt < 4; ++nt) {
        unsigned short us[4];
#pragma unroll
        for (int r = 0; r < 4; ++r)
            us[r] = bf16rne(fexp2((acc[nt][r] - 1.0f) * SCALE_));
#pragma unroll
        for (int r = 0; r < 4; ++r)
            Ms[rloc + qq * 4 + r][nt * 16 + m] = us[r];
        uint2 t;
        t.x = (unsigned)us[0] | ((unsigned)us[1] << 16);
        t.y = (unsigned)us[2] | ((unsigned)us[3] << 16);
        *(uint2*)&MsT[nt * 16 + m][rloc + qq * 4] = t;
    }
    __syncthreads();
    // coalesced stores: 64 rows x 128B each, 8 lanes per row, uint4 x2 per thread
#pragma unroll
    for (int s = 0; s < 2; ++s) {
        int idx = tid + 256 * s;
        int row = idx >> 3, seg = idx & 7;
        *(uint4*)(M + ((size_t)b << 20) + ((size_t)(i0 + row) << 10) + j0 + seg * 8) =
            *(const uint4*)&Ms[row][seg * 8];
        *(uint4*)(MT + ((size_t)b << 20) + ((size_t)(j0 + row) << 10) + i0 + seg * 8) =
            *(const uint4*)&MsT[row][seg * 8];
    }
}

// ---------------- persistent Sinkhorn (R1-proven loop, verbatim) + fused GEMM tail ----------------
// Tail: out = diag(exp2(u*S)) * (M_rows @ W) + V, per-block independent.
// A = this block's own M rows (already in registers from the preload) staged to LDS;
// W built per-64-j-chunk in LDS with the exact wt_kernel math (bit-identical to the
// old global WT); wj from proven agent-atomic v loads; sa from register uprev.
// MFMA sequence == old gemm_final instruction-for-instruction -> bit-identical output.
// No cross-block traffic, no new synchronization.
#define ACC8(U4, base)                                              \
    s0 = fmaf(bflo(U4.x), wrg[base + 0], s0);                       \
    s1 = fmaf(__uint_as_float(U4.x), wrg[base + 1], s1);            \
    s0 = fmaf(bflo(U4.y), wrg[base + 2], s0);                       \
    s1 = fmaf(__uint_as_float(U4.y), wrg[base + 3], s1);            \
    s0 = fmaf(bflo(U4.z), wrg[base + 4], s0);                       \
    s1 = fmaf(__uint_as_float(U4.z), wrg[base + 5], s1);            \
    s0 = fmaf(bflo(U4.w), wrg[base + 6], s0);                       \
    s1 = fmaf(__uint_as_float(U4.w), wrg[base + 7], s1);

__global__ __launch_bounds__(256, 1) void sink_coop(const unsigned short* __restrict__ M,
                                                    const unsigned short* __restrict__ MT,
                                                    float* __restrict__ u,
                                                    float* __restrict__ v,
                                                    unsigned long long* __restrict__ cnt64,
                                                    const float* __restrict__ V,
                                                    float* __restrict__ out,
                                                    float eln) {
    __shared__ __align__(16) float sw[1280];   // pitch-20 padded
    __shared__ float sdel[4];
    __shared__ int sflag;
    // tail-only LDS (total static ~101KB <= 160KB; 1 block/CU placement unchanged)
    __shared__ __align__(16) unsigned short Mslab[32 * MPITCH];  // 66,048 B
    __shared__ __align__(16) float Vs[64][65];                   // 16,640 B
    __shared__ __align__(16) unsigned short WTl[64 * 72];        // 9,216 B
    __shared__ float wjL[1024];                                  // 4,096 B
    __shared__ float sa[32];
    int tid = threadIdx.x;
    int w = tid >> 6, lane = tid & 63;
    int b = blockIdx.x & 7;
    int slice = blockIdx.x >> 3;          // 0..31
    int rbase = slice * 32 + w * 8;       // wave's first local row
    const unsigned short* Mb  = M  + ((size_t)b << 20);
    const unsigned short* MTb = MT + ((size_t)b << 20);
    float* ub = u + (b << 10);
    float* vb = v + (b << 10);

    // ---- preload this wave's 8 M-rows + 8 MT-rows into registers ----
    uint4 mA[8], mB[8], nA[8], nB[8];
#pragma unroll
    for (int r = 0; r < 8; ++r) {
        const uint4* rp = (const uint4*)(Mb + ((size_t)(rbase + r) << 10));
        mA[r] = rp[lane * 2];
        mB[r] = rp[lane * 2 + 1];
        const uint4* tp = (const uint4*)(MTb + ((size_t)(rbase + r) << 10));
        nA[r] = tp[lane * 2];
        nB[r] = tp[lane * 2 + 1];
    }

    float uprev[8];
#pragma unroll
    for (int r = 0; r < 8; ++r) uprev[r] = 0.f;

    unsigned myerr = 0xffffffffu;   // tid0: this batch's fixed-point err sum for iter t

    for (int t = 0; t < MAX_ITER; ++t) {
        // ---------- u phase ----------
        {
            float4 ex;
            ex.x = fexp2(__hip_atomic_load(vb + tid * 4 + 0, __ATOMIC_RELAXED, __HIP_MEMORY_SCOPE_AGENT) * SCALE_);
            ex.y = fexp2(__hip_atomic_load(vb + tid * 4 + 1, __ATOMIC_RELAXED, __HIP_MEMORY_SCOPE_AGENT) * SCALE_);
            ex.z = fexp2(__hip_atomic_load(vb + tid * 4 + 2, __ATOMIC_RELAXED, __HIP_MEMORY_SCOPE_AGENT) * SCALE_);
            ex.w = fexp2(__hip_atomic_load(vb + tid * 4 + 3, __ATOMIC_RELAXED, __HIP_MEMORY_SCOPE_AGENT) * SCALE_);
            *(float4*)&sw[tid * 4 + 4 * (tid >> 2)] = ex;
            __syncthreads();
            float wrg[16];
            *(float4*)&wrg[0]  = *(const float4*)&sw[lane * 20 + 0];
            *(float4*)&wrg[4]  = *(const float4*)&sw[lane * 20 + 4];
            *(float4*)&wrg[8]  = *(const float4*)&sw[lane * 20 + 8];
            *(float4*)&wrg[12] = *(const float4*)&sw[lane * 20 + 12];
            float del = 0.f;
#pragma unroll
            for (int rr = 0; rr < 8; ++rr) {
                float s0 = 0.f, s1 = 0.f;
                ACC8(mA[rr], 0)
                ACC8(mB[rr], 8)
                float s = wave_sum64(s0 + s1);
                float un = eln - EPSLN2_ * flog2(s);
                del += fabsf(un - uprev[rr]);
                uprev[rr] = un;
                if (lane == 0)
                    __hip_atomic_store(ub + rbase + rr, un, __ATOMIC_RELAXED, __HIP_MEMORY_SCOPE_AGENT);
            }
            if (lane == 0) sdel[w] = del;
            asm volatile("s_waitcnt vmcnt(0)" ::: "memory");
            __syncthreads();
            if (tid == 0) {
                float dsum = sdel[0] + sdel[1] + sdel[2] + sdel[3];
                unsigned dfx = (unsigned)fminf(dsum * 1048576.0f, 6.0e7f) + 1u;
                unsigned long long* c = cnt64 + CNT64IDX(2 * t, b);
                unsigned long long tot =
                    __hip_atomic_fetch_add(c, (1ULL << 32) | (unsigned long long)dfx,
                                           __ATOMIC_RELAXED, __HIP_MEMORY_SCOPE_AGENT) +
                    ((1ULL << 32) | (unsigned long long)dfx);
                while ((unsigned)(tot >> 32) < NPER) {
                    __builtin_amdgcn_s_sleep(1);
                    tot = __hip_atomic_load(c, __ATOMIC_RELAXED, __HIP_MEMORY_SCOPE_AGENT);
                }
                myerr = (unsigned)tot;   // final once count==NPER; reused in v phase
            }
            __syncthreads();
        }
        // ---------- v phase ----------
        {
            float4 ex;
            ex.x = fexp2(__hip_atomic_load(ub + tid * 4 + 0, __ATOMIC_RELAXED, __HIP_MEMORY_SCOPE_AGENT) * SCALE_);
            ex.y = fexp2(__hip_atomic_load(ub + tid * 4 + 1, __ATOMIC_RELAXED, __HIP_MEMORY_SCOPE_AGENT) * SCALE_);
            ex.z = fexp2(__hip_atomic_load(ub + tid * 4 + 2, __ATOMIC_RELAXED, __HIP_MEMORY_SCOPE_AGENT) * SCALE_);
            ex.w = fexp2(__hip_atomic_load(ub + tid * 4 + 3, __ATOMIC_RELAXED, __HIP_MEMORY_SCOPE_AGENT) * SCALE_);
            *(float4*)&sw[tid * 4 + 4 * (tid >> 2)] = ex;
            __syncthreads();
            float wrg[16];
            *(float4*)&wrg[0]  = *(const float4*)&sw[lane * 20 + 0];
            *(float4*)&wrg[4]  = *(const float4*)&sw[lane * 20 + 4];
            *(float4*)&wrg[8]  = *(const float4*)&sw[lane * 20 + 8];
            *(float4*)&wrg[12] = *(const float4*)&sw[lane * 20 + 12];
#pragma unroll
            for (int rr = 0; rr < 8; ++rr) {
                float s0 = 0.f, s1 = 0.f;
                ACC8(nA[rr], 0)
                ACC8(nB[rr], 8)
                float s = wave_sum64(s0 + s1);
                float vn = eln - EPSLN2_ * flog2(s);
                if (lane == 0)
                    __hip_atomic_store(vb + rbase + rr, vn, __ATOMIC_RELAXED, __HIP_MEMORY_SCOPE_AGENT);
            }
            asm volatile("s_waitcnt vmcnt(0)" ::: "memory");
            __syncthreads();
            if (tid == 0) {
                unsigned long long* c = cnt64 + CNT64IDX(2 * t + 1, b);
                unsigned long long tot =
                    __hip_atomic_fetch_add(c, 1ULL << 32, __ATOMIC_RELAXED, __HIP_MEMORY_SCOPE_AGENT) +
                    (1ULL << 32);
                while ((unsigned)(tot >> 32) < NPER) {
                    __builtin_amdgcn_s_sleep(1);
                    tot = __hip_atomic_load(c, __ATOMIC_RELAXED, __HIP_MEMORY_SCOPE_AGENT);
                }
                int brk = 0;
                if (myerr < ERR_FX_THRESH) {
                    // rare path: no batch can break before the global sum crosses the
                    // threshold, so every batch's u-counter for t reaches NPER.
                    unsigned long long s = 0;
                    for (int bb = 0; bb < 8; ++bb) {
                        unsigned long long tv = __hip_atomic_load(cnt64 + CNT64IDX(2 * t, bb),
                                                                  __ATOMIC_RELAXED, __HIP_MEMORY_SCOPE_AGENT);
                        while ((unsigned)(tv >> 32) < NPER) {
                            __builtin_amdgcn_s_sleep(1);
                            tv = __hip_atomic_load(cnt64 + CNT64IDX(2 * t, bb),
                                                   __ATOMIC_RELAXED, __HIP_MEMORY_SCOPE_AGENT);
                        }
                        s += (unsigned long long)(unsigned)tv;
                    }
                    brk = (s < (unsigned long long)ERR_FX_THRESH);
                }
                sflag = brk;
            }
            __syncthreads();
            if (sflag) break;
        }
    }

    // ---------------- fused GEMM tail ----------------
    {
        // wj for ALL 1024 j of this batch (v final + agent-visible after the loop's
        // last barrier; atomic loads are the proven cross-XCD-safe mechanism)
        {
            float a0 = __hip_atomic_load(vb + tid * 4 + 0, __ATOMIC_RELAXED, __HIP_MEMORY_SCOPE_AGENT);
            float a1 = __hip_atomic_load(vb + tid * 4 + 1, __ATOMIC_RELAXED, __HIP_MEMORY_SCOPE_AGENT);
            float a2 = __hip_atomic_load(vb + tid * 4 + 2, __ATOMIC_RELAXED, __HIP_MEMORY_SCOPE_AGENT);
            float a3 = __hip_atomic_load(vb + tid * 4 + 3, __ATOMIC_RELAXED, __HIP_MEMORY_SCOPE_AGENT);
            wjL[tid * 4 + 0] = fexp2(a0 * SCALE_);
            wjL[tid * 4 + 1] = fexp2(a1 * SCALE_);
            wjL[tid * 4 + 2] = fexp2(a2 * SCALE_);
            wjL[tid * 4 + 3] = fexp2(a3 * SCALE_);
        }
        // sa from register-resident uprev (lane-uniform after wave_sum64)
#pragma unroll
        for (int r = 0; r < 8; ++r)
            if (lane == r) sa[w * 8 + r] = fexp2(uprev[r] * SCALE_);
        // stage this block's raw M rows from registers into Mslab (A operand)
#pragma unroll
        for (int r = 0; r < 8; ++r) {
            int row = w * 8 + r;
            *(uint4*)&Mslab[row * MPITCH + lane * 16]     = mA[r];
            *(uint4*)&Mslab[row * MPITCH + lane * 16 + 8] = mB[r];
        }
        int m2 = lane & 15, q2 = lane >> 4;
        int rloc2 = (w & 1) * 16;
        int nbase2 = (w >> 1) * 32;
        f32x4 acc0 = {0.f, 0.f, 0.f, 0.f}, acc1 = {0.f, 0.f, 0.f, 0.f};
        const float* Vb2 = V + ((size_t)b << 16);
        for (int jc = 0; jc < 16; ++jc) {
            // stage V chunk rows jc*64..+64 (16KB f32)
#pragma unroll
            for (int c = 0; c < 4; ++c) {
                int idx = tid + 256 * c;
                int row = idx >> 4, c4 = idx & 15;
                float4 x = ((const float4*)(Vb2 + ((size_t)(jc * 64 + row) << 6)))[c4];
                Vs[row][c4 * 4 + 0] = x.x; Vs[row][c4 * 4 + 1] = x.y;
                Vs[row][c4 * 4 + 2] = x.z; Vs[row][c4 * 4 + 3] = x.w;
            }
            __syncthreads();   // Vs ready (chunk 0: also wjL/Mslab staging complete)
            // build WTl[d][j-local] = bf16(wj_j * V[j][d]) — exact wt_kernel math
            {
                int d = tid >> 2, qd = tid & 3;
                unsigned pk[8];
#pragma unroll
                for (int p = 0; p < 8; ++p) {
                    int j = qd * 16 + p * 2;
                    unsigned lo = bf16rne(Vs[j][d] * wjL[jc * 64 + j]);
                    unsigned hi = bf16rne(Vs[j + 1][d] * wjL[jc * 64 + j + 1]);
                    pk[p] = lo | (hi << 16);
                }
                unsigned short* dst = &WTl[d * 72 + qd * 16];
                ((uint4*)dst)[0] = make_uint4(pk[0], pk[1], pk[2], pk[3]);
                ((uint4*)dst)[1] = make_uint4(pk[4], pk[5], pk[6], pk[7]);
            }
            __syncthreads();   // WTl ready; next chunk's Vs overwrite is fenced by the
                               // next iteration's first sync (all waves pass MFMA first)
            // MFMA: identical term order to the old gemm_final k0 loop
            short8 a0 = *(const short8*)&Mslab[(rloc2 + m2) * MPITCH + jc * 64 + q2 * 8];
            short8 a1 = *(const short8*)&Mslab[(rloc2 + m2) * MPITCH + jc * 64 + q2 * 8 + 32];
            short8 b00 = *(const short8*)&WTl[(nbase2 + m2) * 72 + q2 * 8];
            short8 b01 = *(const short8*)&WTl[(nbase2 + m2) * 72 + q2 * 8 + 32];
            short8 b10 = *(const short8*)&WTl[(nbase2 + m2 + 16) * 72 + q2 * 8];
            short8 b11 = *(const short8*)&WTl[(nbase2 + m2 + 16) * 72 + q2 * 8 + 32];
            acc0 = __builtin_amdgcn_mfma_f32_16x16x32_bf16(a0, b00, acc0, 0, 0, 0);
            acc1 = __builtin_amdgcn_mfma_f32_16x16x32_bf16(a0, b10, acc1, 0, 0, 0);
            acc0 = __builtin_amdgcn_mfma_f32_16x16x32_bf16(a1, b01, acc0, 0, 0, 0);
            acc1 = __builtin_amdgcn_mfma_f32_16x16x32_bf16(a1, b11, acc1, 0, 0, 0);
        }
        // epilogue: identical to the old gemm_final (rows = slice*32..+32)
#pragma unroll
        for (int r = 0; r < 4; ++r) {
            int lrow = rloc2 + q2 * 4 + r;
            int gm = slice * 32 + lrow;
            float a = sa[lrow];
            size_t base = (((size_t)b << 10) + gm) * DD;
            int n0 = nbase2 + m2;
            out[base + n0]      = fmaf(a, acc0[r], V[base + n0]);
            out[base + n0 + 16] = fmaf(a, acc1[r], V[base + n0 + 16]);
        }
    }
}

extern "C" void kernel_launch(void* const* d_in, const int* in_sizes, int n_in,
                              void* d_out, int out_size, void* d_ws, size_t ws_size,
                              hipStream_t stream) {
    const float* q = (const float*)d_in[0];
    const float* k = (const float*)d_in[1];
    const float* V = (const float*)d_in[2];
    float* out = (float*)d_out;

    char* ws = (char*)d_ws;
    const size_t MB16 = (size_t)BB * NN * NN * sizeof(unsigned short);   // 16 MB
    unsigned short* M  = (unsigned short*)ws;
    unsigned short* MT = (unsigned short*)(ws + MB16);
    float* u   = (float*)(ws + 2 * MB16);
    float* v   = u + BB * NN;                               // u+v = 64 KiB
    unsigned long long* cnt64 = (unsigned long long*)(v + BB * NN);   // 1600 u64 = 12,800 B
    // u, v, cnt64 contiguous: 65,536 + 12,800 = 78,336 B (proven bound)

    // out-as-scratch: Qn (1MB) || Kn (1MB) = exactly out's 2MB. Qn/Kn are consumed
    // by cost_kernel, which completes before sink's tail writes out (stream-ordered).
    unsigned short* Qn = (unsigned short*)out;
    unsigned short* Kn = Qn + (size_t)BB * NN * DD;

    norm_kernel<<<256, 256, 0, stream>>>(q, k, Qn, Kn);

    // metadata zeroing folded into cost_kernel block (0,0,0): v + cnt64 only
    cost_kernel<<<dim3(16, 16, 8), 256, 0, stream>>>(Qn, Kn, M, MT, v);

    float eln = EPSF * logf(1.0f / NN + 1e-8f);
    // REGULAR launch: barrier is hand-rolled; ~101KB LDS keeps 1 block/CU, the
    // placement we already had at 256 blocks / 256 CUs. Failure mode if placement
    // ever splits: visible hang, not silent corruption.
    sink_coop<<<dim3(NBLK), dim3(256), 0, stream>>>(M, MT, u, v, cnt64, V, out, eln);
}